// Round 6
// baseline (4712.232 us; speedup 1.0000x reference)
//
#include <hip/hip_runtime.h>
#include <math.h>

#define BB   64
#define CC   1024
#define HWC  144
#define KK   8192
#define MM   9216
#define NBN  64          // number of 128-code partial-softmax blocks

typedef __attribute__((ext_vector_type(8)))  short          bf16x8;
typedef __attribute__((ext_vector_type(8)))  unsigned short u16x8;
typedef __attribute__((ext_vector_type(4)))  float          f32x4;
typedef __attribute__((ext_vector_type(16))) float          f32x16;

// ws byte layout
#define FA_BYTES  ((size_t)MM * CC * 2 * 2)   // hi+lo bf16
#define FB_BYTES  ((size_t)KK * CC * 2 * 2)
#define OFF_FA    0
#define OFF_FB    (OFF_FA + FA_BYTES)
#define OFF_ESQ   (OFF_FB + FB_BYTES)
#define OFF_PM    (OFF_ESQ + (size_t)KK * 4)
#define OFF_PS    (OFF_PM + (size_t)NBN * MM * 4)
#define OFF_FACT  (OFF_PS + (size_t)NBN * MM * 4)

__device__ inline unsigned short f2bf(float x) {
    union { float f; unsigned u; } v; v.f = x;
    unsigned r = v.u + 0x7fffu + ((v.u >> 16) & 1u);
    return (unsigned short)(r >> 16);
}
__device__ inline float bf2f(unsigned short h) {
    union { unsigned u; float f; } v; v.u = (unsigned)h << 16;
    return v.f;
}

// ---------------------------------------------------------------------------
// Prep A: crop + transpose + bf16 hi/lo split into 256-row BK=16 tiles.
// Tile (bm,kt) = 16 KB: [h(2)][oct(2)][row(256)] x 16B; oct = k-octet.
__global__ __launch_bounds__(256)
void prep_A(const float* __restrict__ feat, u16x8* __restrict__ fA) {
    __shared__ float tile[64][145];
    int cb = blockIdx.x;      // 16 channel blocks of 64
    int b  = blockIdx.y;
    for (int idx = threadIdx.x; idx < 64 * 144; idx += 256) {
        int r = idx / 144, hw = idx - r * 144;
        int h = hw / 12, w = hw - h * 12;
        tile[r][hw] = feat[(size_t)((b * 1024 + cb * 64 + r) * 196)
                           + (h + 1) * 14 + (w + 1)];
    }
    __syncthreads();
    for (int idx = threadIdx.x; idx < 8 * 144; idx += 256) {
        int g = idx / 144, hw = idx - g * 144;       // hw fastest -> coalesced
        int p = b * 144 + hw;
        int bm = p >> 8, row = p & 255;
        int c = cb * 64 + g * 8;
        int kt = c >> 4, oct = (c >> 3) & 1;
        u16x8 hi, lo;
#pragma unroll
        for (int e = 0; e < 8; ++e) {
            float x = tile[g * 8 + e][hw];
            unsigned short h16 = f2bf(x);
            hi[e] = (short)h16;
            lo[e] = (short)f2bf(x - bf2f(h16));
        }
        size_t base = ((size_t)bm * 64 + kt) * 1024 + oct * 256 + row;
        fA[base] = hi;
        fA[base + 512] = lo;
    }
}

// Prep B: LDS-tiled transpose of embedding into the same tiling.
__global__ __launch_bounds__(256)
void prep_B(const float* __restrict__ emb, u16x8* __restrict__ fB) {
    __shared__ float tile[128][65];
    int cb = blockIdx.x;      // 16 channel blocks of 64
    int nb = blockIdx.y;      // 64 n blocks of 128
#pragma unroll
    for (int i = 0; i < 8; ++i) {
        int idx = threadIdx.x + i * 256;             // < 2048
        int nl = idx >> 4, c4 = idx & 15;
        const float4 v = *reinterpret_cast<const float4*>(
            emb + (size_t)(nb * 128 + nl) * 1024 + cb * 64 + c4 * 4);
        tile[nl][c4 * 4 + 0] = v.x;
        tile[nl][c4 * 4 + 1] = v.y;
        tile[nl][c4 * 4 + 2] = v.z;
        tile[nl][c4 * 4 + 3] = v.w;
    }
    __syncthreads();
#pragma unroll
    for (int i = 0; i < 4; ++i) {
        int idx = threadIdx.x + i * 256;             // < 1024
        int kc = idx >> 7, rl = idx & 127;           // rl fastest -> coalesced
        int c = cb * 64 + kc * 8;
        int kt = c >> 4, oct = (c >> 3) & 1;
        int n = nb * 128 + rl;
        int bn = n >> 8, row = n & 255;
        u16x8 hi, lo;
#pragma unroll
        for (int e = 0; e < 8; ++e) {
            float x = tile[rl][kc * 8 + e];
            unsigned short h16 = f2bf(x);
            hi[e] = (short)h16;
            lo[e] = (short)f2bf(x - bf2f(h16));
        }
        size_t base = ((size_t)bn * 64 + kt) * 1024 + oct * 256 + row;
        fB[base] = hi;
        fB[base + 512] = lo;
    }
}

// Row sum-of-squares for embedding (fp32 exact)
__global__ void rowsumsq(const float* __restrict__ src, float* __restrict__ dst) {
    int row = blockIdx.x * 4 + (threadIdx.x >> 6);
    int l = threadIdx.x & 63;
    const float4* p = reinterpret_cast<const float4*>(src + (size_t)row * 1024);
    float s = 0.f;
#pragma unroll
    for (int it = 0; it < 4; ++it) {
        float4 v = p[l + it * 64];
        s += v.x * v.x + v.y * v.y + v.z * v.z + v.w * v.w;
    }
#pragma unroll
    for (int off = 32; off; off >>= 1) s += __shfl_down(s, off);
    if (l == 0) dst[row] = s;
}

// ---------------------------------------------------------------------------
// 256x256 MFMA GEMM (bf16x3 split, 32x32x16) + fused partial softmax.
// 4 waves (2x2, each 128x128), BK=16, 2x32KB LDS dbuf -> 2 blocks/CU.
__global__ __launch_bounds__(256, 2)
void gemm_mfma(const char* __restrict__ fA, const char* __restrict__ fB,
               const float* __restrict__ esq, const float* __restrict__ mdm,
               float* __restrict__ codes, float* __restrict__ pm,
               float* __restrict__ ps) {
    __shared__ __align__(16) char smem[65536];

    int flat = blockIdx.x;                    // 1152 = 8 * 144
    int swz = (flat & 7) * 144 + (flat >> 3); // XCD-aware, bijective
    int bm = swz >> 5, bn = swz & 31;

    int tid = threadIdx.x;
    int l = tid & 63, l31 = l & 31, lc2 = l >> 5;
    int wv = tid >> 6, wr = wv >> 1, wc = wv & 1;

    const char* gA = fA + (size_t)bm * 1048576;   // 64 kt * 16 KB
    const char* gB = fB + (size_t)bn * 1048576;

    f32x16 acc[4][4];
#pragma unroll
    for (int i = 0; i < 4; ++i)
#pragma unroll
        for (int j = 0; j < 4; ++j)
#pragma unroll
            for (int r = 0; r < 16; ++r) acc[i][j][r] = 0.f;

    auto stage = [&](int buf, int kt) {
        char* db = smem + buf * 32768;
        const char* ga = gA + (size_t)kt * 16384;
        const char* gb = gB + (size_t)kt * 16384;
#pragma unroll
        for (int i = 0; i < 4; ++i) {
            int off = i * 4096 + tid * 16;
            __builtin_amdgcn_global_load_lds(
                (const __attribute__((address_space(1))) void*)(ga + off),
                (__attribute__((address_space(3))) void*)(db + off), 16, 0, 0);
            __builtin_amdgcn_global_load_lds(
                (const __attribute__((address_space(1))) void*)(gb + off),
                (__attribute__((address_space(3))) void*)(db + 16384 + off), 16, 0, 0);
        }
    };

    stage(0, 0);
    stage(1, 1);                 // 16 loads/wave outstanding

    for (int kt = 0; kt < 64; ++kt) {
        // tile kt done when only tile kt+1's 8 loads remain in flight
        asm volatile("s_waitcnt vmcnt(8)" ::: "memory");
        __builtin_amdgcn_s_barrier();
        __builtin_amdgcn_sched_barrier(0);

        const char* bufc = smem + (kt & 1) * 32768;
        // A frags: row = wr*128 + fi*32 + l31, k-octet = lc2
        bf16x8 ah[4], al[4], bh[4], bl[4];
#pragma unroll
        for (int f = 0; f < 4; ++f) {
            int ao = (lc2 * 256 + wr * 128 + f * 32 + l31) * 16;
            ah[f] = *(const bf16x8*)(bufc + ao);
            al[f] = *(const bf16x8*)(bufc + 8192 + ao);
            int bo = 16384 + (lc2 * 256 + wc * 128 + f * 32 + l31) * 16;
            bh[f] = *(const bf16x8*)(bufc + bo);
            bl[f] = *(const bf16x8*)(bufc + 8192 + bo);
        }
        __builtin_amdgcn_s_setprio(1);
#pragma unroll
        for (int fi = 0; fi < 4; ++fi)
#pragma unroll
            for (int fj = 0; fj < 4; ++fj) {
                f32x16& A = acc[fi][fj];
                A = __builtin_amdgcn_mfma_f32_32x32x16_bf16(ah[fi], bh[fj], A, 0, 0, 0);
                A = __builtin_amdgcn_mfma_f32_32x32x16_bf16(ah[fi], bl[fj], A, 0, 0, 0);
                A = __builtin_amdgcn_mfma_f32_32x32x16_bf16(al[fi], bh[fj], A, 0, 0, 0);
            }
        __builtin_amdgcn_s_setprio(0);
        __builtin_amdgcn_s_barrier();        // all waves done reading buf
        int kn = (kt + 2 > 63) ? 63 : kt + 2; // clamp keeps counts uniform
        stage(kt & 1, kn);
    }

    // ---- fused partial-softmax epilogue (base-2 domain), per-wave 128 cols --
    float invl2 = (15.0f / mdm[0]) * 1.44269504089f;
    float s2 = 2.0f * invl2;
    float e2[4];
#pragma unroll
    for (int fj = 0; fj < 4; ++fj)
        e2[fj] = invl2 * esq[bn * 256 + wc * 128 + fj * 32 + l31];

    int bnp = bn * 2 + wc;                   // partial-softmax block id

#pragma unroll
    for (int fi = 0; fi < 4; ++fi) {
        float mx[16], ss[16];
#pragma unroll
        for (int fj = 0; fj < 4; ++fj)
#pragma unroll
            for (int r = 0; r < 16; ++r)
                acc[fi][fj][r] = s2 * acc[fi][fj][r] - e2[fj];
#pragma unroll
        for (int r = 0; r < 16; ++r)
            mx[r] = fmaxf(fmaxf(acc[fi][0][r], acc[fi][1][r]),
                          fmaxf(acc[fi][2][r], acc[fi][3][r]));
#pragma unroll
        for (int off = 1; off < 32; off <<= 1)
#pragma unroll
            for (int r = 0; r < 16; ++r)
                mx[r] = fmaxf(mx[r], __shfl_xor(mx[r], off));
#pragma unroll
        for (int r = 0; r < 16; ++r) ss[r] = 0.f;
#pragma unroll
        for (int fj = 0; fj < 4; ++fj)
#pragma unroll
            for (int r = 0; r < 16; ++r) {
                float E = exp2f(acc[fi][fj][r] - mx[r]);
                acc[fi][fj][r] = E;
                ss[r] += E;
            }
#pragma unroll
        for (int off = 1; off < 32; off <<= 1)
#pragma unroll
            for (int r = 0; r < 16; ++r)
                ss[r] += __shfl_xor(ss[r], off);

        if (l31 == 0) {
#pragma unroll
            for (int r = 0; r < 16; ++r) {
                int row = wr * 128 + fi * 32 + 8 * (r >> 2) + 4 * lc2 + (r & 3);
                int p = bm * 256 + row;
                pm[(size_t)bnp * MM + p] = mx[r];
                ps[(size_t)bnp * MM + p] = ss[r];
            }
        }

        // NT-store E: rows 8q+4*lc2+0..3 contiguous in hw
#pragma unroll
        for (int fj = 0; fj < 4; ++fj) {
            int k = bn * 256 + wc * 128 + fj * 32 + l31;
#pragma unroll
            for (int q = 0; q < 4; ++q) {
                int p0 = bm * 256 + wr * 128 + fi * 32 + 8 * q + 4 * lc2;
                int b = p0 / 144, hw = p0 - b * 144;
                f32x4 v;
                v.x = acc[fi][fj][q * 4 + 0];
                v.y = acc[fi][fj][q * 4 + 1];
                v.z = acc[fi][fj][q * 4 + 2];
                v.w = acc[fi][fj][q * 4 + 3];
                __builtin_nontemporal_store(
                    v, (f32x4*)(codes + ((size_t)(b * 8192 + k)) * 144 + hw));
            }
        }
    }
}

// ---------------------------------------------------------------------------
// Combine partials: factor[bnp][p] = 2^(pm - m_glob) / S
__global__ void comb_factor(const float* __restrict__ pm,
                            const float* __restrict__ ps,
                            float* __restrict__ factor) {
    int p = blockIdx.x * 256 + threadIdx.x;      // 9216 = 36*256
    float m = -INFINITY;
#pragma unroll 8
    for (int bn = 0; bn < NBN; ++bn) m = fmaxf(m, pm[(size_t)bn * MM + p]);
    float S = 0.f;
#pragma unroll 8
    for (int bn = 0; bn < NBN; ++bn)
        S += ps[(size_t)bn * MM + p] * exp2f(pm[(size_t)bn * MM + p] - m);
    float is = 1.f / S;
#pragma unroll 8
    for (int bn = 0; bn < NBN; ++bn)
        factor[(size_t)bn * MM + p] = exp2f(pm[(size_t)bn * MM + p] - m) * is;
}

// ---------------------------------------------------------------------------
// codes = E * factor (in place), bow[r] = max over hw. One wave per row.
__global__ __launch_bounds__(256)
void scale_bow(float* __restrict__ codes, const float* __restrict__ factor,
               float* __restrict__ bow) {
    int wid = threadIdx.x >> 6, l = threadIdx.x & 63;
    int r = blockIdx.x * 4 + wid;                // b*8192 + k
    int b = r >> 13, k = r & 8191;
    f32x4* Cp = (f32x4*)(codes + (size_t)r * 144);
    const f32x4* Fp = (const f32x4*)(factor + (size_t)(k >> 7) * MM + b * 144);
    float m = 0.f;
    if (l < 36) {
        f32x4 e = __builtin_nontemporal_load(Cp + l);
        f32x4 f = Fp[l];
        f32x4 v = e * f;
        __builtin_nontemporal_store(v, Cp + l);
        m = fmaxf(fmaxf(v.x, v.y), fmaxf(v.z, v.w));
    }
#pragma unroll
    for (int off = 32; off; off >>= 1) m = fmaxf(m, __shfl_down(m, off));
    if (l == 0) bow[r] = m;
}

// L1-normalize bow per b
__global__ void bow_norm(float* __restrict__ bow) {
    __shared__ float lds[4];
    __shared__ float stot;
    int b = blockIdx.x;
    float* p = bow + b * 8192;
    float s = 0.f;
    for (int i = threadIdx.x; i < 8192; i += 256) s += fabsf(p[i]);
#pragma unroll
    for (int off = 32; off; off >>= 1) s += __shfl_down(s, off);
    int wid = threadIdx.x >> 6, l = threadIdx.x & 63;
    if (l == 0) lds[wid] = s;
    __syncthreads();
    if (threadIdx.x == 0) stot = 1.f / (lds[0] + lds[1] + lds[2] + lds[3]);
    __syncthreads();
    float inv = stot;
    for (int i = threadIdx.x; i < 8192; i += 256) p[i] *= inv;
}

// ---------------------------------------------------------------------------
extern "C" void kernel_launch(void* const* d_in, const int* in_sizes, int n_in,
                              void* d_out, int out_size, void* d_ws, size_t ws_size,
                              hipStream_t stream) {
    const float* feat = (const float*)d_in[0];
    const float* emb  = (const float*)d_in[1];
    const float* mdm  = (const float*)d_in[2];
    float* bow   = (float*)d_out;
    float* codes = (float*)d_out + (size_t)BB * KK;

    char* ws = (char*)d_ws;
    u16x8* fA    = (u16x8*)(ws + OFF_FA);
    u16x8* fB    = (u16x8*)(ws + OFF_FB);
    float* esq   = (float*)(ws + OFF_ESQ);
    float* pm    = (float*)(ws + OFF_PM);
    float* ps    = (float*)(ws + OFF_PS);
    float* fact  = (float*)(ws + OFF_FACT);

    prep_A<<<dim3(16, 64), 256, 0, stream>>>(feat, fA);
    prep_B<<<dim3(16, 64), 256, 0, stream>>>(emb, fB);
    rowsumsq<<<KK / 4, 256, 0, stream>>>(emb, esq);
    gemm_mfma<<<1152, 256, 0, stream>>>((const char*)fA, (const char*)fB,
                                        esq, mdm, codes, pm, ps);
    comb_factor<<<36, 256, 0, stream>>>(pm, ps, fact);
    scale_bow<<<(BB * KK) / 4, 256, 0, stream>>>(codes, fact, bow);
    bow_norm<<<BB, 256, 0, stream>>>(bow);
}

// Round 7
// 644.808 us; speedup vs baseline: 7.3080x; 7.3080x over previous
//
#include <hip/hip_runtime.h>
#include <math.h>

#define BB   64
#define CC   1024
#define HWC  144
#define KK   8192
#define MM   9216
#define NBN  128         // number of 64-code partial-softmax blocks

typedef __attribute__((ext_vector_type(8)))  short          bf16x8;
typedef __attribute__((ext_vector_type(8)))  unsigned short u16x8;
typedef __attribute__((ext_vector_type(4)))  float          f32x4;
typedef __attribute__((ext_vector_type(16))) float          f32x16;

// ws byte layout
#define FA_BYTES  ((size_t)MM * CC * 2 * 2)   // hi+lo bf16
#define FB_BYTES  ((size_t)KK * CC * 2 * 2)
#define OFF_FA    0
#define OFF_FB    (OFF_FA + FA_BYTES)
#define OFF_ESQ   (OFF_FB + FB_BYTES)
#define OFF_PM    (OFF_ESQ + (size_t)KK * 4)
#define OFF_PS    (OFF_PM + (size_t)NBN * MM * 4)
#define OFF_FACT  (OFF_PS + (size_t)NBN * MM * 4)

__device__ inline unsigned short f2bf(float x) {
    union { float f; unsigned u; } v; v.f = x;
    unsigned r = v.u + 0x7fffu + ((v.u >> 16) & 1u);
    return (unsigned short)(r >> 16);
}
__device__ inline float bf2f(unsigned short h) {
    union { unsigned u; float f; } v; v.u = (unsigned)h << 16;
    return v.f;
}

// ---------------------------------------------------------------------------
// Prep A: crop + transpose + bf16 hi/lo split into 256-row BK=16 tiles.
// Tile (bm,kt) = 16 KB: hi [oct(2)][row(256)]x16B, then lo (+512 slots).
__global__ __launch_bounds__(256)
void prep_A(const float* __restrict__ feat, u16x8* __restrict__ fA) {
    __shared__ float tile[64][145];
    int cb = blockIdx.x;      // 16 channel blocks of 64
    int b  = blockIdx.y;
    for (int idx = threadIdx.x; idx < 64 * 144; idx += 256) {
        int r = idx / 144, hw = idx - r * 144;
        int h = hw / 12, w = hw - h * 12;
        tile[r][hw] = feat[(size_t)((b * 1024 + cb * 64 + r) * 196)
                           + (h + 1) * 14 + (w + 1)];
    }
    __syncthreads();
    for (int idx = threadIdx.x; idx < 8 * 144; idx += 256) {
        int g = idx / 144, hw = idx - g * 144;       // hw fastest -> coalesced
        int p = b * 144 + hw;
        int bm = p >> 8, row = p & 255;
        int c = cb * 64 + g * 8;
        int kt = c >> 4, oct = (c >> 3) & 1;
        u16x8 hi, lo;
#pragma unroll
        for (int e = 0; e < 8; ++e) {
            float x = tile[g * 8 + e][hw];
            unsigned short h16 = f2bf(x);
            hi[e] = (short)h16;
            lo[e] = (short)f2bf(x - bf2f(h16));
        }
        size_t base = ((size_t)bm * 64 + kt) * 1024 + oct * 256 + row;
        fA[base] = hi;
        fA[base + 512] = lo;
    }
}

// Prep B: 128-col tiles. Tile (bn,kt) = 8 KB: hi [oct(2)][col(128)]x16B, lo +256.
__global__ __launch_bounds__(256)
void prep_B(const float* __restrict__ emb, u16x8* __restrict__ fB) {
    __shared__ float tile[128][65];
    int cb = blockIdx.x;      // 16 channel blocks of 64
    int nb = blockIdx.y;      // 64 n blocks of 128 (== bn)
#pragma unroll
    for (int i = 0; i < 8; ++i) {
        int idx = threadIdx.x + i * 256;             // < 2048
        int nl = idx >> 4, c4 = idx & 15;
        const float4 v = *reinterpret_cast<const float4*>(
            emb + (size_t)(nb * 128 + nl) * 1024 + cb * 64 + c4 * 4);
        tile[nl][c4 * 4 + 0] = v.x;
        tile[nl][c4 * 4 + 1] = v.y;
        tile[nl][c4 * 4 + 2] = v.z;
        tile[nl][c4 * 4 + 3] = v.w;
    }
    __syncthreads();
#pragma unroll
    for (int i = 0; i < 4; ++i) {
        int idx = threadIdx.x + i * 256;             // < 1024
        int kc = idx >> 7, rl = idx & 127;           // rl fastest -> coalesced
        int c = cb * 64 + kc * 8;
        int kt = c >> 4, oct = (c >> 3) & 1;
        u16x8 hi, lo;
#pragma unroll
        for (int e = 0; e < 8; ++e) {
            float x = tile[rl][kc * 8 + e];
            unsigned short h16 = f2bf(x);
            hi[e] = (short)h16;
            lo[e] = (short)f2bf(x - bf2f(h16));
        }
        size_t base = ((size_t)nb * 64 + kt) * 512 + oct * 128 + rl;
        fB[base] = hi;
        fB[base + 256] = lo;
    }
}

// Row sum-of-squares for embedding (fp32 exact)
__global__ void rowsumsq(const float* __restrict__ src, float* __restrict__ dst) {
    int row = blockIdx.x * 4 + (threadIdx.x >> 6);
    int l = threadIdx.x & 63;
    const float4* p = reinterpret_cast<const float4*>(src + (size_t)row * 1024);
    float s = 0.f;
#pragma unroll
    for (int it = 0; it < 4; ++it) {
        float4 v = p[l + it * 64];
        s += v.x * v.x + v.y * v.y + v.z * v.z + v.w * v.w;
    }
#pragma unroll
    for (int off = 32; off; off >>= 1) s += __shfl_down(s, off);
    if (l == 0) dst[row] = s;
}

// ---------------------------------------------------------------------------
// 256x128 MFMA GEMM (bf16x3 split, 32x32x16) + fused partial softmax.
// 4 waves (2x2), each wave 128x64 via 4x2 frags -> acc 128 VGPR (no spill).
// BK=16, 2x24KB LDS dbuf -> 2 blocks/CU. Counted vmcnt(6) pipeline.
__global__ __launch_bounds__(256, 2)
void gemm_mfma(const char* __restrict__ fA, const char* __restrict__ fB,
               const float* __restrict__ esq, const float* __restrict__ mdm,
               float* __restrict__ codes, float* __restrict__ pm,
               float* __restrict__ ps) {
    __shared__ __align__(16) char smem[49152];

    int flat = blockIdx.x;                    // 2304 = 8 * 288
    int swz = (flat & 7) * 288 + (flat >> 3); // XCD-aware, bijective
    int bm = swz >> 6, bn = swz & 63;         // 36 x 64

    int tid = threadIdx.x;
    int l = tid & 63, l31 = l & 31, lc2 = l >> 5;
    int wv = tid >> 6, wr = wv >> 1, wc = wv & 1;

    const char* gA = fA + (size_t)bm * 1048576;   // 64 kt * 16 KB
    const char* gB = fB + (size_t)bn * 524288;    // 64 kt * 8 KB

    f32x16 acc[4][2];
#pragma unroll
    for (int i = 0; i < 4; ++i)
#pragma unroll
        for (int j = 0; j < 2; ++j)
#pragma unroll
            for (int r = 0; r < 16; ++r) acc[i][j][r] = 0.f;

    auto stage = [&](int buf, int kt) {
        char* db = smem + buf * 24576;
        const char* ga = gA + (size_t)kt * 16384;
        const char* gb = gB + (size_t)kt * 8192;
#pragma unroll
        for (int i = 0; i < 4; ++i) {
            int off = i * 4096 + tid * 16;
            __builtin_amdgcn_global_load_lds(
                (const __attribute__((address_space(1))) void*)(ga + off),
                (__attribute__((address_space(3))) void*)(db + off), 16, 0, 0);
        }
#pragma unroll
        for (int i = 0; i < 2; ++i) {
            int off = i * 4096 + tid * 16;
            __builtin_amdgcn_global_load_lds(
                (const __attribute__((address_space(1))) void*)(gb + off),
                (__attribute__((address_space(3))) void*)(db + 16384 + off), 16, 0, 0);
        }
    };

    stage(0, 0);
    stage(1, 1);                 // 12 loads/wave outstanding

    for (int kt = 0; kt < 64; ++kt) {
        // tile kt done when only tile kt+1's 6 loads remain in flight
        asm volatile("s_waitcnt vmcnt(6)" ::: "memory");
        __builtin_amdgcn_s_barrier();
        __builtin_amdgcn_sched_barrier(0);

        const char* bufc = smem + (kt & 1) * 24576;
        bf16x8 ah[4], al[4], bh[2], bl[2];
#pragma unroll
        for (int f = 0; f < 4; ++f) {
            int ao = (lc2 * 256 + wr * 128 + f * 32 + l31) * 16;
            ah[f] = *(const bf16x8*)(bufc + ao);
            al[f] = *(const bf16x8*)(bufc + 8192 + ao);
        }
#pragma unroll
        for (int f = 0; f < 2; ++f) {
            int bo = 16384 + (lc2 * 128 + wc * 64 + f * 32 + l31) * 16;
            bh[f] = *(const bf16x8*)(bufc + bo);
            bl[f] = *(const bf16x8*)(bufc + 4096 + bo);
        }
        __builtin_amdgcn_s_setprio(1);
#pragma unroll
        for (int fi = 0; fi < 4; ++fi)
#pragma unroll
            for (int fj = 0; fj < 2; ++fj) {
                f32x16& A = acc[fi][fj];
                A = __builtin_amdgcn_mfma_f32_32x32x16_bf16(ah[fi], bh[fj], A, 0, 0, 0);
                A = __builtin_amdgcn_mfma_f32_32x32x16_bf16(ah[fi], bl[fj], A, 0, 0, 0);
                A = __builtin_amdgcn_mfma_f32_32x32x16_bf16(al[fi], bh[fj], A, 0, 0, 0);
            }
        __builtin_amdgcn_s_setprio(0);
        __builtin_amdgcn_s_barrier();        // all waves done reading buf
        int kn = (kt + 2 > 63) ? 63 : kt + 2; // clamp keeps counts uniform
        stage(kt & 1, kn);
    }

    // ---- fused partial-softmax epilogue (base-2 domain), per-wave 64 cols --
    float invl2 = (15.0f / mdm[0]) * 1.44269504089f;
    float s2 = 2.0f * invl2;
    float e2[2];
#pragma unroll
    for (int fj = 0; fj < 2; ++fj)
        e2[fj] = invl2 * esq[bn * 128 + wc * 64 + fj * 32 + l31];

    int bnp = bn * 2 + wc;                   // partial-softmax block id

#pragma unroll
    for (int fi = 0; fi < 4; ++fi) {
        float mx[16], ss[16];
#pragma unroll
        for (int fj = 0; fj < 2; ++fj)
#pragma unroll
            for (int r = 0; r < 16; ++r)
                acc[fi][fj][r] = s2 * acc[fi][fj][r] - e2[fj];
#pragma unroll
        for (int r = 0; r < 16; ++r)
            mx[r] = fmaxf(acc[fi][0][r], acc[fi][1][r]);
#pragma unroll
        for (int off = 1; off < 32; off <<= 1)
#pragma unroll
            for (int r = 0; r < 16; ++r)
                mx[r] = fmaxf(mx[r], __shfl_xor(mx[r], off));
#pragma unroll
        for (int r = 0; r < 16; ++r) ss[r] = 0.f;
#pragma unroll
        for (int fj = 0; fj < 2; ++fj)
#pragma unroll
            for (int r = 0; r < 16; ++r) {
                float E = exp2f(acc[fi][fj][r] - mx[r]);
                acc[fi][fj][r] = E;
                ss[r] += E;
            }
#pragma unroll
        for (int off = 1; off < 32; off <<= 1)
#pragma unroll
            for (int r = 0; r < 16; ++r)
                ss[r] += __shfl_xor(ss[r], off);

        if (l31 == 0) {
#pragma unroll
            for (int r = 0; r < 16; ++r) {
                int row = wr * 128 + fi * 32 + 8 * (r >> 2) + 4 * lc2 + (r & 3);
                int p = bm * 256 + row;
                pm[(size_t)bnp * MM + p] = mx[r];
                ps[(size_t)bnp * MM + p] = ss[r];
            }
        }

        // NT-store E: rows 8q+4*lc2+0..3 contiguous in hw
#pragma unroll
        for (int fj = 0; fj < 2; ++fj) {
            int k = bn * 128 + wc * 64 + fj * 32 + l31;
#pragma unroll
            for (int q = 0; q < 4; ++q) {
                int p0 = bm * 256 + wr * 128 + fi * 32 + 8 * q + 4 * lc2;
                int b = p0 / 144, hw = p0 - b * 144;
                f32x4 v;
                v.x = acc[fi][fj][q * 4 + 0];
                v.y = acc[fi][fj][q * 4 + 1];
                v.z = acc[fi][fj][q * 4 + 2];
                v.w = acc[fi][fj][q * 4 + 3];
                __builtin_nontemporal_store(
                    v, (f32x4*)(codes + ((size_t)(b * 8192 + k)) * 144 + hw));
            }
        }
    }
}

// ---------------------------------------------------------------------------
// Combine partials: factor[bnp][p] = 2^(pm - m_glob) / S
__global__ void comb_factor(const float* __restrict__ pm,
                            const float* __restrict__ ps,
                            float* __restrict__ factor) {
    int p = blockIdx.x * 256 + threadIdx.x;      // 9216 = 36*256
    float m = -INFINITY;
#pragma unroll 8
    for (int bn = 0; bn < NBN; ++bn) m = fmaxf(m, pm[(size_t)bn * MM + p]);
    float S = 0.f;
#pragma unroll 8
    for (int bn = 0; bn < NBN; ++bn)
        S += ps[(size_t)bn * MM + p] * exp2f(pm[(size_t)bn * MM + p] - m);
    float is = 1.f / S;
#pragma unroll 8
    for (int bn = 0; bn < NBN; ++bn)
        factor[(size_t)bn * MM + p] = exp2f(pm[(size_t)bn * MM + p] - m) * is;
}

// ---------------------------------------------------------------------------
// codes = E * factor (in place), bow[r] = max over hw. One wave per row.
__global__ __launch_bounds__(256)
void scale_bow(float* __restrict__ codes, const float* __restrict__ factor,
               float* __restrict__ bow) {
    int wid = threadIdx.x >> 6, l = threadIdx.x & 63;
    int r = blockIdx.x * 4 + wid;                // b*8192 + k
    int b = r >> 13, k = r & 8191;
    f32x4* Cp = (f32x4*)(codes + (size_t)r * 144);
    const f32x4* Fp = (const f32x4*)(factor + (size_t)(k >> 6) * MM + b * 144);
    float m = 0.f;
    if (l < 36) {
        f32x4 e = __builtin_nontemporal_load(Cp + l);
        f32x4 f = Fp[l];
        f32x4 v = e * f;
        __builtin_nontemporal_store(v, Cp + l);
        m = fmaxf(fmaxf(v.x, v.y), fmaxf(v.z, v.w));
    }
#pragma unroll
    for (int off = 32; off; off >>= 1) m = fmaxf(m, __shfl_down(m, off));
    if (l == 0) bow[r] = m;
}

// L1-normalize bow per b
__global__ void bow_norm(float* __restrict__ bow) {
    __shared__ float lds[4];
    __shared__ float stot;
    int b = blockIdx.x;
    float* p = bow + b * 8192;
    float s = 0.f;
    for (int i = threadIdx.x; i < 8192; i += 256) s += fabsf(p[i]);
#pragma unroll
    for (int off = 32; off; off >>= 1) s += __shfl_down(s, off);
    int wid = threadIdx.x >> 6, l = threadIdx.x & 63;
    if (l == 0) lds[wid] = s;
    __syncthreads();
    if (threadIdx.x == 0) stot = 1.f / (lds[0] + lds[1] + lds[2] + lds[3]);
    __syncthreads();
    float inv = stot;
    for (int i = threadIdx.x; i < 8192; i += 256) p[i] *= inv;
}

// ---------------------------------------------------------------------------
extern "C" void kernel_launch(void* const* d_in, const int* in_sizes, int n_in,
                              void* d_out, int out_size, void* d_ws, size_t ws_size,
                              hipStream_t stream) {
    const float* feat = (const float*)d_in[0];
    const float* emb  = (const float*)d_in[1];
    const float* mdm  = (const float*)d_in[2];
    float* bow   = (float*)d_out;
    float* codes = (float*)d_out + (size_t)BB * KK;

    char* ws = (char*)d_ws;
    u16x8* fA    = (u16x8*)(ws + OFF_FA);
    u16x8* fB    = (u16x8*)(ws + OFF_FB);
    float* esq   = (float*)(ws + OFF_ESQ);
    float* pm    = (float*)(ws + OFF_PM);
    float* ps    = (float*)(ws + OFF_PS);
    float* fact  = (float*)(ws + OFF_FACT);

    prep_A<<<dim3(16, 64), 256, 0, stream>>>(feat, fA);
    prep_B<<<dim3(16, 64), 256, 0, stream>>>(emb, fB);
    rowsumsq<<<KK / 4, 256, 0, stream>>>(emb, esq);
    gemm_mfma<<<2304, 256, 0, stream>>>((const char*)fA, (const char*)fB,
                                        esq, mdm, codes, pm, ps);
    comb_factor<<<36, 256, 0, stream>>>(pm, ps, fact);
    scale_bow<<<(BB * KK) / 4, 256, 0, stream>>>(codes, fact, bow);
    bow_norm<<<BB, 256, 0, stream>>>(bow);
}